// Round 1
// 342.128 us; speedup vs baseline: 1.3583x; 1.3583x over previous
//
#include <hip/hip_runtime.h>

typedef unsigned short u16;
typedef unsigned int   u32;
typedef __attribute__((ext_vector_type(8))) short short8;   // 8 bf16 (4 VGPRs)
typedef __attribute__((ext_vector_type(4))) float floatx4;  // MFMA acc

#define T_DIM 4096
#define D_DIM 2048
#define H_DIM 256
#define M_DIM 16384   // B*T
#define NFLAT 8192    // D*W

__device__ __forceinline__ u16 f2bf(float f) {
  union { float f; u32 u; } c; c.f = f;
  u32 x = c.u;
  x += 0x7FFFu + ((x >> 16) & 1u);   // RNE
  return (u16)(x >> 16);
}
__device__ __forceinline__ u32 pk2(float a, float b) {
  return (u32)f2bf(a) | ((u32)f2bf(b) << 16);
}

// async global->LDS, 16B per lane. LDS dest = wave-uniform base + lane*16.
__device__ __forceinline__ void glds16(const void* g, void* l) {
  __builtin_amdgcn_global_load_lds(
      (const __attribute__((address_space(1))) void*)g,
      (__attribute__((address_space(3))) void*)l, 16, 0, 0);
}

// ---------------- transpose + fp32->bf16 convert: src[R][C] -> dst[C][R] ----
__global__ void __launch_bounds__(256) tr_cvt(const float* __restrict__ src,
                                              u16* __restrict__ dst, int R, int C) {
  __shared__ u16 tile[32][33];
  const int tx = threadIdx.x & 31;
  const int ty = threadIdx.x >> 5;        // 0..7
  const int c0 = blockIdx.x * 32;
  const int r0 = blockIdx.y * 32;
  #pragma unroll
  for (int i = ty; i < 32; i += 8)
    tile[i][tx] = f2bf(src[(size_t)(r0 + i) * C + (c0 + tx)]);
  __syncthreads();
  #pragma unroll
  for (int i = ty; i < 32; i += 8)
    dst[(size_t)(c0 + i) * R + (r0 + tx)] = tile[tx][i];
}

// ---------------- GEMM1: h = silu(x @ w1), fp32 x inline-cvt ----------------
// tile 64(M) x 128(N), BK=64 -> 32 k-iters. grid = (2, 256) = 512 blocks.
// 4 waves (2My x 2Nx), wave tile 32x64 -> acc[2][4].
// LDS XOR-swizzle: col16 chunk c holds global chunk c ^ (row&7) (involution).
__global__ void __launch_bounds__(256) gemm1_silu(const float* __restrict__ X,   // [M][2048]
                                                  const u16* __restrict__ Bt,    // w1t [256][2048]
                                                  u16* __restrict__ H) {         // [M][256]
  __shared__ __align__(16) u16 As[64][64];    //  8 KB (row stride 128 B)
  __shared__ __align__(16) u16 Bs[128][64];   // 16 KB
  const int tid  = threadIdx.x;
  const int lane = tid & 63, l15 = lane & 15, quad = lane >> 4;
  const int wv   = tid >> 6, wy = wv >> 1, wx = wv & 1;
  const int m0   = blockIdx.y * 64;
  const int n0   = blockIdx.x * 128;
  const int srow = lane >> 3, sc = lane & 7;   // glds chunk: row-in-chunk, col16

  floatx4 acc[2][4];
  const floatx4 zf = {0.f, 0.f, 0.f, 0.f};
  #pragma unroll
  for (int i = 0; i < 2; ++i)
    #pragma unroll
    for (int j = 0; j < 4; ++j) acc[i][j] = zf;

  // prologue: load A(k=0) fp32 into regs. thread -> chunk s: row=s>>3, g=s&7.
  float4 fA[2][2];
  #pragma unroll
  for (int i = 0; i < 2; ++i) {
    int s = i * 256 + tid, row = s >> 3, g = s & 7;
    const float* xs = &X[(size_t)(m0 + row) * D_DIM + g * 8];
    fA[i][0] = *(const float4*)xs;
    fA[i][1] = *(const float4*)(xs + 4);
  }

  for (int k0 = 0; k0 < D_DIM; k0 += 64) {
    __syncthreads();                          // prev frag reads done, fA loads drained
    #pragma unroll
    for (int i = 0; i < 2; ++i) {             // As: cvt + swizzled ds_write
      int s = i * 256 + tid, row = s >> 3, g = s & 7, c = g ^ (row & 7);
      uint4 pk;
      pk.x = pk2(fA[i][0].x, fA[i][0].y);
      pk.y = pk2(fA[i][0].z, fA[i][0].w);
      pk.z = pk2(fA[i][1].x, fA[i][1].y);
      pk.w = pk2(fA[i][1].z, fA[i][1].w);
      *(uint4*)&As[row][c * 8] = pk;
    }
    #pragma unroll
    for (int ci = 0; ci < 4; ++ci) {          // Bs: glds16, pre-swizzled source
      int ch  = ci * 4 + wv;
      int row = ch * 8 + srow;
      glds16(&Bt[(size_t)(n0 + row) * D_DIM + k0 + (sc ^ (row & 7)) * 8],
             (char*)Bs + ch * 1024);
    }
    __syncthreads();                          // As written, Bs landed
    {                                         // prefetch next A under MFMA phase
      int kn = (k0 + 64 < D_DIM) ? (k0 + 64) : 0;
      #pragma unroll
      for (int i = 0; i < 2; ++i) {
        int s = i * 256 + tid, row = s >> 3, g = s & 7;
        const float* xs = &X[(size_t)(m0 + row) * D_DIM + kn + g * 8];
        fA[i][0] = *(const float4*)xs;
        fA[i][1] = *(const float4*)(xs + 4);
      }
    }
    short8 af[2][2], bfr[4][2];
    #pragma unroll
    for (int ks = 0; ks < 2; ++ks) {
      #pragma unroll
      for (int mi = 0; mi < 2; ++mi) {
        int row = wy * 32 + mi * 16 + l15;
        af[mi][ks] = *(const short8*)&As[row][((ks * 4 + quad) ^ (row & 7)) * 8];
      }
      #pragma unroll
      for (int ni = 0; ni < 4; ++ni) {
        int row = wx * 64 + ni * 16 + l15;
        bfr[ni][ks] = *(const short8*)&Bs[row][((ks * 4 + quad) ^ (row & 7)) * 8];
      }
    }
    #pragma unroll
    for (int ks = 0; ks < 2; ++ks)
      #pragma unroll
      for (int mi = 0; mi < 2; ++mi)
        #pragma unroll
        for (int ni = 0; ni < 4; ++ni)
          acc[mi][ni] = __builtin_amdgcn_mfma_f32_16x16x32_bf16(af[mi][ks], bfr[ni][ks], acc[mi][ni], 0, 0, 0);
  }
  #pragma unroll
  for (int mi = 0; mi < 2; ++mi)
    #pragma unroll
    for (int ni = 0; ni < 4; ++ni)
      #pragma unroll
      for (int r = 0; r < 4; ++r) {
        float v = acc[mi][ni][r];
        v = v / (1.f + __expf(-v));
        int row = m0 + wy * 32 + mi * 16 + quad * 4 + r;
        int col = n0 + wx * 64 + ni * 16 + l15;
        H[(size_t)row * H_DIM + col] = f2bf(v);
      }
}

// ---- GEMM2 fused: flat = h @ w2 + b2 ; out = silu(conv(flat, x)) ----------
// tile 128 tokens x 128 flat cols (=32 d-channels). BK=64 -> 4 k-iters.
// B rows PERMUTED at stage time so flat col = d*4 + ni: the 4 conv taps of a
// channel live in ONE lane across the ni register index -> register epilogue,
// no LDS round-trip, no epilogue barriers.
__global__ void __launch_bounds__(256) gemm2_conv_silu(const u16* __restrict__ Hin,   // [M][256] bf16
                                                       const u16* __restrict__ Bt,    // w2t [8192][256] bf16
                                                       const float* __restrict__ bias,// [8192] fp32
                                                       const float* __restrict__ X,   // [M][2048] fp32
                                                       float* __restrict__ Out) {     // [M][2048] fp32
  __shared__ __align__(16) u16 As[128][64];   // 16 KB
  __shared__ __align__(16) u16 Bs[128][64];   // 16 KB
  const int tid  = threadIdx.x;
  const int lane = tid & 63, l15 = lane & 15, quad = lane >> 4;
  const int wv   = tid >> 6, wy = wv >> 1, wx = wv & 1;
  const int m0   = blockIdx.y * 128;
  const int d0   = blockIdx.x * 32;
  const int srow = lane >> 3, sc = lane & 7;

  floatx4 acc[4][4];
  const floatx4 zf = {0.f, 0.f, 0.f, 0.f};
  #pragma unroll
  for (int i = 0; i < 4; ++i)
    #pragma unroll
    for (int j = 0; j < 4; ++j) acc[i][j] = zf;

  for (int k0 = 0; k0 < H_DIM; k0 += 64) {    // 4 iterations
    __syncthreads();
    #pragma unroll
    for (int ci = 0; ci < 4; ++ci) {
      int ch  = ci * 4 + wv;                  // 16 chunks of 1 KB each
      int row = ch * 8 + srow;                // 0..127
      int g   = (sc ^ (row & 7)) * 8;         // swizzled k-chunk source
      glds16(&Hin[(size_t)(m0 + row) * H_DIM + k0 + g], (char*)As + ch * 1024);
      // permuted w2t row: Bs row (wx*64+ni*16+l15) <-> flat col (d0+wx*16+l15)*4+ni
      int fc = (d0 + ((row >> 6) << 4) + (row & 15)) * 4 + ((row >> 4) & 3);
      glds16(&Bt[(size_t)fc * H_DIM + k0 + g], (char*)Bs + ch * 1024);
    }
    __syncthreads();
    short8 af[4][2], bfr[4][2];
    #pragma unroll
    for (int ks = 0; ks < 2; ++ks) {
      #pragma unroll
      for (int mi = 0; mi < 4; ++mi) {
        int row = wy * 64 + mi * 16 + l15;
        af[mi][ks] = *(const short8*)&As[row][((ks * 4 + quad) ^ (row & 7)) * 8];
      }
      #pragma unroll
      for (int ni = 0; ni < 4; ++ni) {
        int row = wx * 64 + ni * 16 + l15;
        bfr[ni][ks] = *(const short8*)&Bs[row][((ks * 4 + quad) ^ (row & 7)) * 8];
      }
    }
    #pragma unroll
    for (int ks = 0; ks < 2; ++ks)
      #pragma unroll
      for (int mi = 0; mi < 4; ++mi)
        #pragma unroll
        for (int ni = 0; ni < 4; ++ni)
          acc[mi][ni] = __builtin_amdgcn_mfma_f32_16x16x32_bf16(af[mi][ks], bfr[ni][ks], acc[mi][ni], 0, 0, 0);
  }

  // -------- register epilogue: bias + causal conv + silu, no LDS -----------
  const int d     = d0 + wx * 16 + l15;            // this lane's channel
  const float4 bv = *(const float4*)&bias[(size_t)d * 4];  // taps w=0..3
  const int tbase = m0 & (T_DIM - 1);              // tiles never straddle batch
  const int bbase = m0 - tbase;
  const float* xcol = &X[(size_t)bbase * D_DIM + d];
  float* ocol       = &Out[(size_t)m0 * D_DIM + d];

  #pragma unroll
  for (int mi = 0; mi < 4; ++mi) {
    int t0 = wy * 64 + mi * 16 + quad * 4;         // local token of r=0
    int tq = tbase + t0;                           // token within batch
    float xv[7];                                   // x[tq-3 .. tq+3] for this d
    #pragma unroll
    for (int j = 0; j < 7; ++j) {
      int tt = tq - 3 + j;
      xv[j] = (tt >= 0) ? xcol[(size_t)tt * D_DIM] : 0.f;
    }
    #pragma unroll
    for (int r = 0; r < 4; ++r) {
      float c0 = acc[mi][0][r] + bv.x;
      float c1 = acc[mi][1][r] + bv.y;
      float c2 = acc[mi][2][r] + bv.z;
      float c3 = acc[mi][3][r] + bv.w;
      float o  = c0 * xv[r] + c1 * xv[r + 1] + c2 * xv[r + 2] + c3 * xv[r + 3];
      float y  = o / (1.f + __expf(-o));
      ocol[(size_t)(t0 + r) * D_DIM] = y;
    }
  }
}

extern "C" void kernel_launch(void* const* d_in, const int* in_sizes, int n_in,
                              void* d_out, int out_size, void* d_ws, size_t ws_size,
                              hipStream_t stream) {
  const float* x  = (const float*)d_in[0];   // [4,4096,2048]
  const float* w1 = (const float*)d_in[1];   // [2048,256]
  const float* w2 = (const float*)d_in[2];   // [256,8192]
  const float* b2 = (const float*)d_in[3];   // [8192]
  float* out = (float*)d_out;                // [4,4096,2048]

  // ws layout (u16 elems): w1t 512K | w2t 2M | h 4M  (= ~13.6 MB)
  u16* w1t = (u16*)d_ws;                     // [256][2048]
  u16* w2t = w1t + (size_t)H_DIM * D_DIM;    // [8192][256]
  u16* h   = w2t + (size_t)NFLAT * H_DIM;    // [16384][256]

  tr_cvt<<<dim3(H_DIM / 32, D_DIM / 32), 256, 0, stream>>>(w1, w1t, D_DIM, H_DIM);
  tr_cvt<<<dim3(NFLAT / 32, H_DIM / 32), 256, 0, stream>>>(w2, w2t, H_DIM, NFLAT);
  gemm1_silu<<<dim3(2, M_DIM / 64), 256, 0, stream>>>(x, w1t, h);
  gemm2_conv_silu<<<dim3(D_DIM / 32, M_DIM / 128), 256, 0, stream>>>(h, w2t, b2, x, out);
}